// Round 18
// baseline (103.726 us; speedup 1.0000x reference)
//
#include <hip/hip_runtime.h>
#include <stdint.h>

typedef unsigned short u16;
typedef unsigned int   u32;
typedef unsigned char  u8;
typedef __attribute__((ext_vector_type(8))) short short8;
typedef __attribute__((ext_vector_type(4))) float f32x4;
typedef __attribute__((ext_vector_type(4))) unsigned short u16x4;
typedef __attribute__((ext_vector_type(4))) unsigned int u32x4;

#define DEV static __device__ __forceinline__

static constexpr int Bc = 2, Tc = 2048, Hc = 768, NH = 12, HD = 64;
static constexpr int BTc = Bc * Tc;      // 4096 rows
static constexpr int N3 = 3 * Hc;        // 2304
static constexpr int NBH = Bc * NH;      // 24
static constexpr int IPX = 96;           // attn items per XCD (3 heads x 32 qt)
static constexpr float QSCALE = 0.125f * 1.44269504088896f; // 1/sqrt(64) * log2(e)
static constexpr float MRINIT = -1.0e38f;
static constexpr float SMASK  = -3.0e38f;

DEV u16 f2bf(float f) {
  u32 u = __float_as_uint(f);
  u32 r = (u + 0x7fffu + ((u >> 16) & 1u)) >> 16;  // RNE
  return (u16)r;
}

DEV float fexp2(float x) {
#if __has_builtin(__builtin_amdgcn_exp2f)
  return __builtin_amdgcn_exp2f(x);
#else
  return exp2f(x);
#endif
}

DEV u32 cvtpk_bf16(float lo, float hi) {  // lo -> bits[15:0], hi -> bits[31:16]
  u32 r;
  asm("v_cvt_pk_bf16_f32 %0, %1, %2" : "=v"(r) : "v"(lo), "v"(hi));
  return r;
}

DEV void gl_lds16(const u16* g, u16* l) {
  __builtin_amdgcn_global_load_lds(
      (const __attribute__((address_space(1))) u32*)g,
      (__attribute__((address_space(3))) u32*)l, 16, 0, 0);
}

#define MFMA(a, b, c) __builtin_amdgcn_mfma_f32_16x16x32_bf16((a), (b), (c), 0, 0, 0)

// ---- prep: weight transposes + x cast + mask flags + queue counters, ONE launch ----
// blocks [0,864): transpose branch; blocks [864, 864+1536): cvt branch. (R14/R16/R17-verified)
__global__ __launch_bounds__(256) void k_prep(const float* __restrict__ x,
                                              const float* __restrict__ Wqkv,
                                              const float* __restrict__ Wproj,
                                              u16* __restrict__ xb,
                                              u16* __restrict__ WqkvT,
                                              u16* __restrict__ WprojT,
                                              const int* __restrict__ mask,
                                              u8* __restrict__ flags,
                                              u32* __restrict__ ctr) {
  const int bid = blockIdx.x, tid = threadIdx.x;
  if (bid == 0 && tid < 64) {
    if (tid < 8) ctr[tid] = 0;
    int b = tid >> 5, kb = tid & 31;
    const int* m = mask + b * Tc + kb * 64;
    int all = 1;
    for (int i = 0; i < 64; ++i) all &= (m[i] != 0);
    flags[b * 32 + kb] = (u8)all;
  }
  if (bid < 864) {
    __shared__ u16 tile[64][65];
    int xg = bid % 36, y = bid / 36;
    const float* in; u16* out; int R, C, r0, c0;
    if (y < 12) { in = Wqkv; out = WqkvT; R = Hc; C = N3; r0 = y * 64; c0 = xg * 64; }
    else {
      if (xg >= 12) return;
      in = Wproj; out = WprojT; R = Hc; C = Hc; r0 = (y - 12) * 64; c0 = xg * 64;
    }
    int tx = tid & 63, ty = tid >> 6;
    for (int i = ty; i < 64; i += 4)
      tile[i][tx] = f2bf(in[(size_t)(r0 + i) * C + c0 + tx]);
    __syncthreads();
    for (int i = ty; i < 64; i += 4)
      out[(size_t)(c0 + i) * R + r0 + tx] = tile[tx][i];
  } else {
    int i = (bid - 864) * 256 + tid;
    if (i >= BTc * Hc / 8) return;
    const float4* in4 = (const float4*)x;
    float4 a = in4[2 * i], b = in4[2 * i + 1];
    uint4 o;
    o.x = f2bf(a.x) | ((u32)f2bf(a.y) << 16);
    o.y = f2bf(a.z) | ((u32)f2bf(a.w) << 16);
    o.z = f2bf(b.x) | ((u32)f2bf(b.y) << 16);
    o.w = f2bf(b.z) | ((u32)f2bf(b.w) << 16);
    ((uint4*)xb)[i] = o;
  }
}

// ---------------- GEMM1: 64x64 tile (4 waves, 2x2 of 32x32), QKV projection ----------------
// R17-verified k_gemm2 ring/staging/frag structure + R16-verified scatter epilogue:
// Q(scaled)/K into [bh][t][d]; V TRANSPOSED + KEY-PERMUTED into VT_perm.
// Grid 36x64 = 2304 blocks = 9/CU (36 waves/CU): K-loop latency fully hidden.
__global__ __launch_bounds__(256) void k_gemm1(const u16* __restrict__ A,
                                               const u16* __restrict__ BTm,
                                               const float* __restrict__ bias,
                                               u16* __restrict__ oQ, u16* __restrict__ oK,
                                               u16* __restrict__ oV, int K) {
  __shared__ u16 As[3][2048];
  __shared__ u16 Bs[3][2048];
  const int tid = threadIdx.x;
  const int lane = tid & 63, wave = tid >> 6;
  const int wr = wave >> 1, wc = wave & 1;

  const int gx = gridDim.x;                       // 36
  const int nwg = gx * gridDim.y;                 // 2304 (div by 8)
  const int lin = blockIdx.y * gx + blockIdx.x;
  const int wg = (lin & 7) * (nwg >> 3) + (lin >> 3);
  const int row0 = (wg / gx) * 64, col0 = (wg % gx) * 64;

  f32x4 acc[2][2];
#pragma unroll
  for (int m = 0; m < 2; ++m)
#pragma unroll
    for (int n = 0; n < 2; ++n) acc[m][n] = (f32x4)(0.f);

  const int srow = lane >> 2;
  const int sg = lane & 3;
  const int sf = (lane >> 3) & 3;
  const int kfetch = ((sg ^ sf) * 8);

  const int r16 = lane & 15;
  const int g = lane >> 4;
  const int fr = (r16 >> 1) & 3;
  const int koff = ((g ^ fr) * 8);

  auto stageG = [&](int slot, int k0) {
    int row = wave * 16 + srow;   // one 16-row segment per wave
    gl_lds16(A + (size_t)(row0 + row) * K + k0 + kfetch, &As[slot][wave * 512 + lane * 8]);
    gl_lds16(BTm + (size_t)(col0 + row) * K + k0 + kfetch, &Bs[slot][wave * 512 + lane * 8]);
  };

  const int nk = K >> 5;  // 24
  stageG(0, 0);
  stageG(1, 32);

  for (int kt = 0; kt < nk; ++kt) {
    if (kt + 1 < nk) asm volatile("s_waitcnt vmcnt(2)" ::: "memory");
    else             asm volatile("s_waitcnt vmcnt(0)" ::: "memory");
    __builtin_amdgcn_sched_barrier(0);
    __builtin_amdgcn_s_barrier();
    __builtin_amdgcn_sched_barrier(0);
    if (kt + 2 < nk) stageG((kt + 2) % 3, (kt + 2) * 32);

    const u16* Ac = &As[kt % 3][0];
    const u16* Bc = &Bs[kt % 3][0];
    short8 af[2], bf[2];
#pragma unroll
    for (int m = 0; m < 2; ++m)
      af[m] = *(const short8*)&Ac[(wr * 32 + m * 16 + r16) * 32 + koff];
#pragma unroll
    for (int n = 0; n < 2; ++n)
      bf[n] = *(const short8*)&Bc[(wc * 32 + n * 16 + r16) * 32 + koff];
#pragma unroll
    for (int m = 0; m < 2; ++m)
#pragma unroll
      for (int n = 0; n < 2; ++n)
        acc[m][n] = MFMA(af[m], bf[n], acc[m][n]);
  }

  // scatter epilogue (R16-verified math; rowg%4==0 within a 2048-row batch half)
#pragma unroll
  for (int m = 0; m < 2; ++m) {
    int rowg = row0 + wr * 32 + m * 16 + g * 4;
#pragma unroll
    for (int n = 0; n < 2; ++n) {
      int colg = col0 + wc * 32 + n * 16 + r16;
      float bv = bias[colg];
      int which = colg / Hc;
      int hc = colg - which * Hc;
      int h = hc >> 6, d = hc & 63;
      int b = rowg >> 11, t0 = rowg & 2047;  // t0 % 4 == 0
      if (which == 2) {
        int o = t0 & 31;
        int t0p = (t0 & ~31) | (((o >> 2) & 3) * 8 + ((o >> 4) & 1) * 4);
        u16x4 pk;
#pragma unroll
        for (int r = 0; r < 4; ++r) pk[r] = f2bf(acc[m][n][r] + bv);
        *(u16x4*)&oV[((size_t)(b * NH + h) * HD + d) * Tc + t0p] = pk;
      } else {
#pragma unroll
        for (int r = 0; r < 4; ++r) {
          float v = acc[m][n][r] + bv;
          size_t dst = ((size_t)(b * NH + h) * Tc + t0 + r) * HD + d;
          if (which == 0) oQ[dst] = f2bf(v * QSCALE);
          else            oK[dst] = f2bf(v);
        }
      }
    }
  }
}

// ---------------- GEMM2: 64x64 tile, out = Ob @ WprojT^T + bias (R17-verified) ----------------
__global__ __launch_bounds__(256) void k_gemm2(const u16* __restrict__ A,
                                               const u16* __restrict__ BTm,
                                               const float* __restrict__ bias,
                                               float* __restrict__ oF, int K) {
  __shared__ u16 As[3][2048];
  __shared__ u16 Bs[3][2048];
  const int tid = threadIdx.x;
  const int lane = tid & 63, wave = tid >> 6;
  const int wr = wave >> 1, wc = wave & 1;

  const int gx = gridDim.x;                       // 12
  const int nwg = gx * gridDim.y;                 // 768 (div by 8)
  const int lin = blockIdx.y * gx + blockIdx.x;
  const int wg = (lin & 7) * (nwg >> 3) + (lin >> 3);
  const int row0 = (wg / gx) * 64, col0 = (wg % gx) * 64;

  f32x4 acc[2][2];
#pragma unroll
  for (int m = 0; m < 2; ++m)
#pragma unroll
    for (int n = 0; n < 2; ++n) acc[m][n] = (f32x4)(0.f);

  const int srow = lane >> 2;
  const int sg = lane & 3;
  const int sf = (lane >> 3) & 3;
  const int kfetch = ((sg ^ sf) * 8);

  const int r16 = lane & 15;
  const int g = lane >> 4;
  const int fr = (r16 >> 1) & 3;
  const int koff = ((g ^ fr) * 8);

  auto stageG = [&](int slot, int k0) {
    int row = wave * 16 + srow;
    gl_lds16(A + (size_t)(row0 + row) * K + k0 + kfetch, &As[slot][wave * 512 + lane * 8]);
    gl_lds16(BTm + (size_t)(col0 + row) * K + k0 + kfetch, &Bs[slot][wave * 512 + lane * 8]);
  };

  const int nk = K >> 5;  // 24
  stageG(0, 0);
  stageG(1, 32);

  for (int kt = 0; kt < nk; ++kt) {
    if (kt + 1 < nk) asm volatile("s_waitcnt vmcnt(2)" ::: "memory");
    else             asm volatile("s_waitcnt vmcnt(0)" ::: "memory");
    __builtin_amdgcn_sched_barrier(0);
    __builtin_amdgcn_s_barrier();
    __builtin_amdgcn_sched_barrier(0);
    if (kt + 2 < nk) stageG((kt + 2) % 3, (kt + 2) * 32);

    const u16* Ac = &As[kt % 3][0];
    const u16* Bc = &Bs[kt % 3][0];
    short8 af[2], bf[2];
#pragma unroll
    for (int m = 0; m < 2; ++m)
      af[m] = *(const short8*)&Ac[(wr * 32 + m * 16 + r16) * 32 + koff];
#pragma unroll
    for (int n = 0; n < 2; ++n)
      bf[n] = *(const short8*)&Bc[(wc * 32 + n * 16 + r16) * 32 + koff];
#pragma unroll
    for (int m = 0; m < 2; ++m)
#pragma unroll
      for (int n = 0; n < 2; ++n)
        acc[m][n] = MFMA(af[m], bf[n], acc[m][n]);
  }

#pragma unroll
  for (int m = 0; m < 2; ++m) {
    int rowg = row0 + wr * 32 + m * 16 + g * 4;
#pragma unroll
    for (int n = 0; n < 2; ++n) {
      int colg = col0 + wc * 32 + n * 16 + r16;
      float bv = bias[colg];
#pragma unroll
      for (int r = 0; r < 4; ++r)
        oF[(size_t)(rowg + r) * Hc + colg] = acc[m][n][r] + bv;
    }
  }
}

// ------ flash attention (R12/R16/R17-verified, 42.5us): KVBLK=64, 8 waves = 4 qgrp x 2 key-half,
// lagged pipeline, 4-slot LDS ring, counted vmcnt, per-XCD queues, P in-register. ------
__global__ __launch_bounds__(512, 4) void k_attn(const u16* __restrict__ Qh,
                                                 const u16* __restrict__ Kh,
                                                 const u16* __restrict__ VT,
                                                 const int* __restrict__ mask,
                                                 const u8* __restrict__ flags,
                                                 u16* __restrict__ O,
                                                 u32* __restrict__ ctr) {
  __shared__ u16 Ks[4][4096];   // [slot][key:64][d:64] swizzled (32KB)
  __shared__ u16 Vs[4][4096];   // [slot][d:64][t:64, key-permuted] swizzled (32KB)
  __shared__ float mlb[128];    // [qgrp][16 q][m,l]
  __shared__ int s_item;
  const int tid = threadIdx.x, lane = tid & 63, wave = tid >> 6;  // 0..7
  const int qgrp = wave >> 1;          // q-group 0..3 (16 rows)
  const int kh = wave & 1;             // key half (32 of 64)
  const int r16 = lane & 15, g = lane >> 4;
  const int r7 = r16 & 7;
  const int skey = lane >> 3;
  const int sgr = lane & 7;
  const int sgd = ((sgr ^ skey) * 8);

  const int off0 = r16 * 64 + ((g ^ r7) * 8);
  const int off1 = r16 * 64 + (((4 + g) ^ r7) * 8);
  const int offv = kh ? off1 : off0;

  const int xcd = blockIdx.x & 7;

  for (;;) {
    if (tid == 0) s_item = (int)atomicAdd(ctr + xcd, 1u);
    __syncthreads();
    const int item = s_item;
    if (item >= IPX) break;
    const int qt = 31 - item / 3;        // LPT descending within XCD
    const int bh = xcd * 3 + item % 3;
    const int b = bh / NH, h = bh - b * NH;
    const int q0 = qt * 64;
    const int nt = qt + 1;
    const int qg = q0 + qgrp * 16 + r16;
    const int* mrow = mask + b * Tc;
    const u8* frow = flags + b * 32;

    const u16* qbase = Qh + ((size_t)bh * Tc + qg) * HD;
    const short8 qf0 = *(const short8*)(qbase + g * 8);
    const short8 qf1 = *(const short8*)(qbase + 32 + g * 8);

    f32x4 acc[4];
#pragma unroll
    for (int n = 0; n < 4; ++n) acc[n] = (f32x4)(0.f);
    float mrun = MRINIT, lrun = 0.f;

    const u16* kgb = Kh + (size_t)bh * Tc * HD;
    const u16* vgb = VT + (size_t)bh * HD * Tc;

    auto stage = [&](int slot, int kb) {
      int rloc = wave * 8 + skey;
      gl_lds16(kgb + (size_t)(kb + rloc) * HD + sgd, &Ks[slot][wave * 512 + lane * 8]);
      gl_lds16(vgb + (size_t)rloc * Tc + kb + sgd, &Vs[slot][wave * 512 + lane * 8]);
    };

    f32x4 sP0, sP1;
    auto process = [&](int u, f32x4 s0, f32x4 s1) {
      const int kbw = 64 * u + 32 * kh;
      const bool diag = (u == nt - 1);
      if (diag || !frow[u]) {
        const int fl = frow[u];
#pragma unroll
        for (int np = 0; np < 2; ++np)
#pragma unroll
          for (int r = 0; r < 4; ++r) {
            int keyg = kbw + 16 * np + 4 * g + r;
            bool ok = fl ? true : (mrow[keyg] != 0);
            if (diag) ok = ok && (keyg <= qg);
            if (!ok) { if (np == 0) s0[r] = SMASK; else s1[r] = SMASK; }
          }
      }
      float lm = fmaxf(fmaxf(fmaxf(s0[0], s0[1]), fmaxf(s0[2], s0[3])),
                       fmaxf(fmaxf(s1[0], s1[1]), fmaxf(s1[2], s1[3])));
      if (!__all(lm <= mrun + 8.0f)) {
        float rm = fmaxf(lm, __shfl_xor(lm, 16));
        rm = fmaxf(rm, __shfl_xor(rm, 32));
        float nm = fmaxf(mrun, rm);
        float alpha = fexp2(mrun - nm);
        mrun = nm;
        lrun *= alpha;
#pragma unroll
        for (int r = 0; r < 4; ++r) {
          float ar = __shfl(alpha, g * 4 + r);
          acc[0][r] *= ar; acc[1][r] *= ar; acc[2][r] *= ar; acc[3][r] *= ar;
        }
      }
      float p0[4], p1[4];
#pragma unroll
      for (int r = 0; r < 4; ++r) {
        p0[r] = fexp2(s0[r] - mrun);
        p1[r] = fexp2(s1[r] - mrun);
      }
      lrun += ((p0[0] + p0[1]) + (p0[2] + p0[3])) + ((p1[0] + p1[1]) + (p1[2] + p1[3]));
      u32x4 PL;
      PL[0] = cvtpk_bf16(p0[0], p0[1]); PL[1] = cvtpk_bf16(p0[2], p0[3]);
      PL[2] = cvtpk_bf16(p1[0], p1[1]); PL[3] = cvtpk_bf16(p1[2], p1[3]);
      short8 pa = __builtin_bit_cast(short8, PL);
      const u16* Vc = &Vs[u & 3][0];
      __builtin_amdgcn_s_setprio(1);
#pragma unroll
      for (int n = 0; n < 4; ++n) {
        short8 vf = *(const short8*)&Vc[n * 1024 + offv];
        acc[n] = MFMA(pa, vf, acc[n]);
      }
      __builtin_amdgcn_s_setprio(0);
    };

    stage(0, 0);
    if (nt > 1) stage(1, 64);

    for (int t = 0; t < nt; ++t) {
      const int kb = t * 64;
      const int rem = nt - 1 - t;

      if (rem >= 1) asm volatile("s_waitcnt vmcnt(2)" ::: "memory");
      else          asm volatile("s_waitcnt vmcnt(0)" ::: "memory");
      __builtin_amdgcn_sched_barrier(0);
      __builtin_amdgcn_s_barrier();
      __builtin_amdgcn_sched_barrier(0);

      if (rem >= 2) stage((t + 2) & 3, kb + 128);

      const u16* Kc = &Ks[t & 3][0];
      f32x4 sN0, sN1;
      __builtin_amdgcn_s_setprio(1);
      {
        const int ng = 2 * kh;
        short8 kf0 = *(const short8*)&Kc[ng * 1024 + off0];
        short8 kf1 = *(const short8*)&Kc[ng * 1024 + off1];
        f32x4 z = (f32x4)(0.f);
        z = MFMA(kf0, qf0, z); z = MFMA(kf1, qf1, z);
        sN0 = z;
        short8 kf2 = *(const short8*)&Kc[(ng + 1) * 1024 + off0];
        short8 kf3 = *(const short8*)&Kc[(ng + 1) * 1024 + off1];
        f32x4 w = (f32x4)(0.f);
        w = MFMA(kf2, qf0, w); w = MFMA(kf3, qf1, w);
        sN1 = w;
      }
      __builtin_amdgcn_s_setprio(0);

      if (t > 0) process(t - 1, sP0, sP1);
      sP0 = sN0; sP1 = sN1;
    }
    process(nt - 1, sP0, sP1);

    // ---- strip end: cross-g l combine, pairwise (m,l,O) merge, store ----
    float lt = lrun + __shfl_xor(lrun, 16);
    lt += __shfl_xor(lt, 32);

    __syncthreads();
    float* ab = (float*)&Ks[0][0] + qgrp * 1024;
    if (kh == 1) {
#pragma unroll
      for (int n = 0; n < 4; ++n)
#pragma unroll
        for (int r = 0; r < 4; ++r)
          ab[(4 * g + r) * 64 + 16 * n + r16] = acc[n][r];
      if (g == 0) {
        mlb[qgrp * 32 + r16 * 2]     = mrun;
        mlb[qgrp * 32 + r16 * 2 + 1] = lt;
      }
    }
    __syncthreads();
    if (kh == 0) {
#pragma unroll
      for (int r = 0; r < 4; ++r) {
        int q = 4 * g + r;
        float mA = __shfl(mrun, q);
        float lA = __shfl(lt, q);
        float mB = mlb[qgrp * 32 + q * 2];
        float lB = mlb[qgrp * 32 + q * 2 + 1];
        float ms = fmaxf(mA, mB);
        float cA = fexp2(mA - ms);
        float cB = fexp2(mB - ms);
        float linv = 1.0f / (lA * cA + lB * cB);
        int qr = q0 + qgrp * 16 + q;
        u16* orow = O + ((size_t)(b * Tc + qr)) * Hc + h * 64;
#pragma unroll
        for (int n = 0; n < 4; ++n) {
          float v = (acc[n][r] * cA + ab[q * 64 + 16 * n + r16] * cB) * linv;
          orow[n * 16 + r16] = f2bf(v);
        }
      }
    }
  }
}

// ---------------- launch ----------------
extern "C" void kernel_launch(void* const* d_in, const int* in_sizes, int n_in,
                              void* d_out, int out_size, void* d_ws, size_t ws_size,
                              hipStream_t stream) {
  const float* x = (const float*)d_in[0];
  const int* mask = (const int*)d_in[1];
  const float* Wqkv = (const float*)d_in[2];
  const float* bqkv = (const float*)d_in[3];
  const float* Wproj = (const float*)d_in[4];
  const float* bproj = (const float*)d_in[5];
  float* out = (float*)d_out;

  char* ws = (char*)d_ws;
  size_t off = 0;
  auto alloc = [&](size_t bytes) {
    char* p = ws + off;
    off += (bytes + 255) & ~(size_t)255;
    return p;
  };
  u16* xb     = (u16*)alloc((size_t)BTc * Hc * 2);
  u16* WqkvT  = (u16*)alloc((size_t)N3 * Hc * 2);
  u16* WprojT = (u16*)alloc((size_t)Hc * Hc * 2);
  u16* Qh     = (u16*)alloc((size_t)BTc * Hc * 2);
  u16* Kh     = (u16*)alloc((size_t)BTc * Hc * 2);
  u16* VT     = (u16*)alloc((size_t)BTc * Hc * 2);
  u32* ctr    = (u32*)alloc(256);
  u8*  flags  = (u8*)alloc(256);
  u16* Ob     = xb;  // alias: xb dead after GEMM1, reused for attention output

  k_prep<<<dim3(864 + BTc * Hc / 8 / 256), 256, 0, stream>>>(
      x, Wqkv, Wproj, xb, WqkvT, WprojT, mask, flags, ctr);
  k_gemm1<<<dim3(36, 64), 256, 0, stream>>>(xb, WqkvT, bqkv, Qh, Kh, VT, Hc);
  k_attn<<<dim3(512), 512, 0, stream>>>(Qh, Kh, VT, mask, flags, Ob, ctr);
  k_gemm2<<<dim3(12, 64), 256, 0, stream>>>(Ob, WprojT, bproj, out, Hc);
}

// Round 19
// 94.438 us; speedup vs baseline: 1.0984x; 1.0984x over previous
//
#include <hip/hip_runtime.h>
#include <stdint.h>

typedef unsigned short u16;
typedef unsigned int   u32;
typedef unsigned char  u8;
typedef __attribute__((ext_vector_type(8))) short short8;
typedef __attribute__((ext_vector_type(4))) float f32x4;
typedef __attribute__((ext_vector_type(4))) unsigned short u16x4;
typedef __attribute__((ext_vector_type(4))) unsigned int u32x4;

#define DEV static __device__ __forceinline__

static constexpr int Bc = 2, Tc = 2048, Hc = 768, NH = 12, HD = 64;
static constexpr int BTc = Bc * Tc;      // 4096 rows
static constexpr int N3 = 3 * Hc;        // 2304
static constexpr int NBH = Bc * NH;      // 24
static constexpr int IPX = 96;           // attn items per XCD (3 heads x 32 qt)
static constexpr float QSCALE = 0.125f * 1.44269504088896f; // 1/sqrt(64) * log2(e)
static constexpr float MRINIT = -1.0e38f;
static constexpr float SMASK  = -3.0e38f;

DEV u16 f2bf(float f) {
  u32 u = __float_as_uint(f);
  u32 r = (u + 0x7fffu + ((u >> 16) & 1u)) >> 16;  // RNE
  return (u16)r;
}

DEV float fexp2(float x) {
#if __has_builtin(__builtin_amdgcn_exp2f)
  return __builtin_amdgcn_exp2f(x);
#else
  return exp2f(x);
#endif
}

DEV u32 cvtpk_bf16(float lo, float hi) {  // lo -> bits[15:0], hi -> bits[31:16]
  u32 r;
  asm("v_cvt_pk_bf16_f32 %0, %1, %2" : "=v"(r) : "v"(lo), "v"(hi));
  return r;
}

DEV void gl_lds16(const u16* g, u16* l) {
  __builtin_amdgcn_global_load_lds(
      (const __attribute__((address_space(1))) u32*)g,
      (__attribute__((address_space(3))) u32*)l, 16, 0, 0);
}

#define MFMA(a, b, c) __builtin_amdgcn_mfma_f32_16x16x32_bf16((a), (b), (c), 0, 0, 0)

// ---- prep: weight transposes + x cast + mask flags + queue counters, ONE launch ----
// blocks [0,864): transpose branch; blocks [864, 864+1536): cvt branch. (R14/R16-verified)
__global__ __launch_bounds__(256) void k_prep(const float* __restrict__ x,
                                              const float* __restrict__ Wqkv,
                                              const float* __restrict__ Wproj,
                                              u16* __restrict__ xb,
                                              u16* __restrict__ WqkvT,
                                              u16* __restrict__ WprojT,
                                              const int* __restrict__ mask,
                                              u8* __restrict__ flags,
                                              u32* __restrict__ ctr) {
  const int bid = blockIdx.x, tid = threadIdx.x;
  if (bid == 0 && tid < 64) {
    if (tid < 8) ctr[tid] = 0;
    int b = tid >> 5, kb = tid & 31;
    const int* m = mask + b * Tc + kb * 64;
    int all = 1;
    for (int i = 0; i < 64; ++i) all &= (m[i] != 0);
    flags[b * 32 + kb] = (u8)all;
  }
  if (bid < 864) {
    __shared__ u16 tile[64][65];
    int xg = bid % 36, y = bid / 36;
    const float* in; u16* out; int R, C, r0, c0;
    if (y < 12) { in = Wqkv; out = WqkvT; R = Hc; C = N3; r0 = y * 64; c0 = xg * 64; }
    else {
      if (xg >= 12) return;
      in = Wproj; out = WprojT; R = Hc; C = Hc; r0 = (y - 12) * 64; c0 = xg * 64;
    }
    int tx = tid & 63, ty = tid >> 6;
    for (int i = ty; i < 64; i += 4)
      tile[i][tx] = f2bf(in[(size_t)(r0 + i) * C + c0 + tx]);
    __syncthreads();
    for (int i = ty; i < 64; i += 4)
      out[(size_t)(c0 + i) * R + r0 + tx] = tile[tx][i];
  } else {
    int i = (bid - 864) * 256 + tid;
    if (i >= BTc * Hc / 8) return;
    const float4* in4 = (const float4*)x;
    float4 a = in4[2 * i], b = in4[2 * i + 1];
    uint4 o;
    o.x = f2bf(a.x) | ((u32)f2bf(a.y) << 16);
    o.y = f2bf(a.z) | ((u32)f2bf(a.w) << 16);
    o.z = f2bf(b.x) | ((u32)f2bf(b.y) << 16);
    o.w = f2bf(b.z) | ((u32)f2bf(b.w) << 16);
    ((uint4*)xb)[i] = o;
  }
}

// ---------------- GEMM1: 128x128 tile, 3-slot ring, counted vmcnt(4), XCD swizzle ----------------
// Scatters Q(scaled)/K into [bh][t][d]; V TRANSPOSED + KEY-PERMUTED into VT_perm.
// (R11/R12/R14/R16/R17-verified; 64x64 variant tried in R18 was SLOWER: staging traffic
// doubles with halved tile and wins over the occupancy gain at this shape.)
__global__ __launch_bounds__(256) void k_gemm(const u16* __restrict__ A,
                                              const u16* __restrict__ BTm,
                                              const float* __restrict__ bias,
                                              u16* __restrict__ oQ, u16* __restrict__ oK,
                                              u16* __restrict__ oV,
                                              int M, int N, int K) {
  __shared__ u16 As[3][4096];
  __shared__ u16 Bs[3][4096];
  const int tid = threadIdx.x;
  const int lane = tid & 63, wave = tid >> 6;
  const int wr = wave >> 1, wc = wave & 1;

  const int gx = gridDim.x;
  const int nwg = gx * gridDim.y;
  const int lin = blockIdx.y * gx + blockIdx.x;
  const int wg = (lin & 7) * (nwg >> 3) + (lin >> 3);
  const int row0 = (wg / gx) * 128, col0 = (wg % gx) * 128;

  f32x4 acc[4][4];
#pragma unroll
  for (int m = 0; m < 4; ++m)
#pragma unroll
    for (int n = 0; n < 4; ++n) acc[m][n] = (f32x4)(0.f);

  const int srow = lane >> 2;
  const int sg = lane & 3;
  const int sf = (lane >> 3) & 3;
  const int kfetch = ((sg ^ sf) * 8);

  const int r16 = lane & 15;
  const int g = lane >> 4;
  const int fr = (r16 >> 1) & 3;
  const int koff = ((g ^ fr) * 8);

  auto stageG = [&](int slot, int k0) {
#pragma unroll
    for (int p = 0; p < 2; ++p) {
      int seg = wave * 2 + p;
      int row = seg * 16 + srow;
      gl_lds16(A + (size_t)(row0 + row) * K + k0 + kfetch, &As[slot][seg * 512 + lane * 8]);
      gl_lds16(BTm + (size_t)(col0 + row) * K + k0 + kfetch, &Bs[slot][seg * 512 + lane * 8]);
    }
  };

  const int nk = K >> 5;
  stageG(0, 0);
  if (nk > 1) stageG(1, 32);

  for (int kt = 0; kt < nk; ++kt) {
    if (kt + 1 < nk) asm volatile("s_waitcnt vmcnt(4)" ::: "memory");
    else             asm volatile("s_waitcnt vmcnt(0)" ::: "memory");
    __builtin_amdgcn_sched_barrier(0);
    __builtin_amdgcn_s_barrier();
    __builtin_amdgcn_sched_barrier(0);
    if (kt + 2 < nk) stageG((kt + 2) % 3, (kt + 2) * 32);

    const u16* Ac = &As[kt % 3][0];
    const u16* Bcur = &Bs[kt % 3][0];
    short8 af[4], bf[4];
#pragma unroll
    for (int m = 0; m < 4; ++m)
      af[m] = *(const short8*)&Ac[(wr * 64 + m * 16 + r16) * 32 + koff];
#pragma unroll
    for (int n = 0; n < 4; ++n)
      bf[n] = *(const short8*)&Bcur[(wc * 64 + n * 16 + r16) * 32 + koff];
#pragma unroll
    for (int m = 0; m < 4; ++m)
#pragma unroll
      for (int n = 0; n < 4; ++n)
        acc[m][n] = MFMA(af[m], bf[n], acc[m][n]);
  }

#pragma unroll
  for (int m = 0; m < 4; ++m) {
    int rowg = row0 + wr * 64 + m * 16 + g * 4;
#pragma unroll
    for (int n = 0; n < 4; ++n) {
      int colg = col0 + wc * 64 + n * 16 + r16;
      float bv = bias[colg];
      int which = colg / Hc;
      int hc = colg - which * Hc;
      int h = hc >> 6, d = hc & 63;
      int b = rowg >> 11, t0 = rowg & 2047;  // t0 % 4 == 0
      if (which == 2) {
        int o = t0 & 31;
        int t0p = (t0 & ~31) | (((o >> 2) & 3) * 8 + ((o >> 4) & 1) * 4);
        u16x4 pk;
#pragma unroll
        for (int r = 0; r < 4; ++r) pk[r] = f2bf(acc[m][n][r] + bv);
        *(u16x4*)&oV[((size_t)(b * NH + h) * HD + d) * Tc + t0p] = pk;
      } else {
#pragma unroll
        for (int r = 0; r < 4; ++r) {
          float v = acc[m][n][r] + bv;
          size_t dst = ((size_t)(b * NH + h) * Tc + t0 + r) * HD + d;
          if (which == 0) oQ[dst] = f2bf(v * QSCALE);
          else            oK[dst] = f2bf(v);
        }
      }
    }
  }
}

// ---------------- GEMM2: 64x64 tile (4 waves, 2x2 of 32x32), out = Ob @ WprojT^T + bias ----
// Same verified ring/staging/frag math with halved extents; 2 gl_lds/wave/stage -> vmcnt(2).
// Grid 12x64 = 768 blocks = 3/CU (12 waves/CU). (R17-verified: GEMM2 15 -> ~7.5us)
__global__ __launch_bounds__(256) void k_gemm2(const u16* __restrict__ A,
                                               const u16* __restrict__ BTm,
                                               const float* __restrict__ bias,
                                               float* __restrict__ oF, int K) {
  __shared__ u16 As[3][2048];
  __shared__ u16 Bs[3][2048];
  const int tid = threadIdx.x;
  const int lane = tid & 63, wave = tid >> 6;
  const int wr = wave >> 1, wc = wave & 1;

  const int gx = gridDim.x;                       // 12
  const int nwg = gx * gridDim.y;                 // 768 (div by 8)
  const int lin = blockIdx.y * gx + blockIdx.x;
  const int wg = (lin & 7) * (nwg >> 3) + (lin >> 3);
  const int row0 = (wg / gx) * 64, col0 = (wg % gx) * 64;

  f32x4 acc[2][2];
#pragma unroll
  for (int m = 0; m < 2; ++m)
#pragma unroll
    for (int n = 0; n < 2; ++n) acc[m][n] = (f32x4)(0.f);

  const int srow = lane >> 2;
  const int sg = lane & 3;
  const int sf = (lane >> 3) & 3;
  const int kfetch = ((sg ^ sf) * 8);

  const int r16 = lane & 15;
  const int g = lane >> 4;
  const int fr = (r16 >> 1) & 3;
  const int koff = ((g ^ fr) * 8);

  auto stageG = [&](int slot, int k0) {
    int row = wave * 16 + srow;   // one 16-row segment per wave
    gl_lds16(A + (size_t)(row0 + row) * K + k0 + kfetch, &As[slot][wave * 512 + lane * 8]);
    gl_lds16(BTm + (size_t)(col0 + row) * K + k0 + kfetch, &Bs[slot][wave * 512 + lane * 8]);
  };

  const int nk = K >> 5;  // 24
  stageG(0, 0);
  stageG(1, 32);

  for (int kt = 0; kt < nk; ++kt) {
    if (kt + 1 < nk) asm volatile("s_waitcnt vmcnt(2)" ::: "memory");
    else             asm volatile("s_waitcnt vmcnt(0)" ::: "memory");
    __builtin_amdgcn_sched_barrier(0);
    __builtin_amdgcn_s_barrier();
    __builtin_amdgcn_sched_barrier(0);
    if (kt + 2 < nk) stageG((kt + 2) % 3, (kt + 2) * 32);

    const u16* Ac = &As[kt % 3][0];
    const u16* Bc = &Bs[kt % 3][0];
    short8 af[2], bf[2];
#pragma unroll
    for (int m = 0; m < 2; ++m)
      af[m] = *(const short8*)&Ac[(wr * 32 + m * 16 + r16) * 32 + koff];
#pragma unroll
    for (int n = 0; n < 2; ++n)
      bf[n] = *(const short8*)&Bc[(wc * 32 + n * 16 + r16) * 32 + koff];
#pragma unroll
    for (int m = 0; m < 2; ++m)
#pragma unroll
      for (int n = 0; n < 2; ++n)
        acc[m][n] = MFMA(af[m], bf[n], acc[m][n]);
  }

#pragma unroll
  for (int m = 0; m < 2; ++m) {
    int rowg = row0 + wr * 32 + m * 16 + g * 4;
#pragma unroll
    for (int n = 0; n < 2; ++n) {
      int colg = col0 + wc * 32 + n * 16 + r16;
      float bv = bias[colg];
#pragma unroll
      for (int r = 0; r < 4; ++r)
        oF[(size_t)(rowg + r) * Hc + colg] = acc[m][n][r] + bv;
    }
  }
}

// ------ flash attention (R12/R16/R17-verified, 42.5us): KVBLK=64, 8 waves = 4 qgrp x 2 key-half,
// lagged pipeline, 4-slot LDS ring, counted vmcnt, per-XCD queues, P in-register. ------
__global__ __launch_bounds__(512, 4) void k_attn(const u16* __restrict__ Qh,
                                                 const u16* __restrict__ Kh,
                                                 const u16* __restrict__ VT,
                                                 const int* __restrict__ mask,
                                                 const u8* __restrict__ flags,
                                                 u16* __restrict__ O,
                                                 u32* __restrict__ ctr) {
  __shared__ u16 Ks[4][4096];   // [slot][key:64][d:64] swizzled (32KB)
  __shared__ u16 Vs[4][4096];   // [slot][d:64][t:64, key-permuted] swizzled (32KB)
  __shared__ float mlb[128];    // [qgrp][16 q][m,l]
  __shared__ int s_item;
  const int tid = threadIdx.x, lane = tid & 63, wave = tid >> 6;  // 0..7
  const int qgrp = wave >> 1;          // q-group 0..3 (16 rows)
  const int kh = wave & 1;             // key half (32 of 64)
  const int r16 = lane & 15, g = lane >> 4;
  const int r7 = r16 & 7;
  const int skey = lane >> 3;
  const int sgr = lane & 7;
  const int sgd = ((sgr ^ skey) * 8);

  const int off0 = r16 * 64 + ((g ^ r7) * 8);
  const int off1 = r16 * 64 + (((4 + g) ^ r7) * 8);
  const int offv = kh ? off1 : off0;

  const int xcd = blockIdx.x & 7;

  for (;;) {
    if (tid == 0) s_item = (int)atomicAdd(ctr + xcd, 1u);
    __syncthreads();
    const int item = s_item;
    if (item >= IPX) break;
    const int qt = 31 - item / 3;        // LPT descending within XCD
    const int bh = xcd * 3 + item % 3;
    const int b = bh / NH, h = bh - b * NH;
    const int q0 = qt * 64;
    const int nt = qt + 1;
    const int qg = q0 + qgrp * 16 + r16;
    const int* mrow = mask + b * Tc;
    const u8* frow = flags + b * 32;

    const u16* qbase = Qh + ((size_t)bh * Tc + qg) * HD;
    const short8 qf0 = *(const short8*)(qbase + g * 8);
    const short8 qf1 = *(const short8*)(qbase + 32 + g * 8);

    f32x4 acc[4];
#pragma unroll
    for (int n = 0; n < 4; ++n) acc[n] = (f32x4)(0.f);
    float mrun = MRINIT, lrun = 0.f;

    const u16* kgb = Kh + (size_t)bh * Tc * HD;
    const u16* vgb = VT + (size_t)bh * HD * Tc;

    auto stage = [&](int slot, int kb) {
      int rloc = wave * 8 + skey;
      gl_lds16(kgb + (size_t)(kb + rloc) * HD + sgd, &Ks[slot][wave * 512 + lane * 8]);
      gl_lds16(vgb + (size_t)rloc * Tc + kb + sgd, &Vs[slot][wave * 512 + lane * 8]);
    };

    f32x4 sP0, sP1;
    auto process = [&](int u, f32x4 s0, f32x4 s1) {
      const int kbw = 64 * u + 32 * kh;
      const bool diag = (u == nt - 1);
      if (diag || !frow[u]) {
        const int fl = frow[u];
#pragma unroll
        for (int np = 0; np < 2; ++np)
#pragma unroll
          for (int r = 0; r < 4; ++r) {
            int keyg = kbw + 16 * np + 4 * g + r;
            bool ok = fl ? true : (mrow[keyg] != 0);
            if (diag) ok = ok && (keyg <= qg);
            if (!ok) { if (np == 0) s0[r] = SMASK; else s1[r] = SMASK; }
          }
      }
      float lm = fmaxf(fmaxf(fmaxf(s0[0], s0[1]), fmaxf(s0[2], s0[3])),
                       fmaxf(fmaxf(s1[0], s1[1]), fmaxf(s1[2], s1[3])));
      if (!__all(lm <= mrun + 8.0f)) {
        float rm = fmaxf(lm, __shfl_xor(lm, 16));
        rm = fmaxf(rm, __shfl_xor(rm, 32));
        float nm = fmaxf(mrun, rm);
        float alpha = fexp2(mrun - nm);
        mrun = nm;
        lrun *= alpha;
#pragma unroll
        for (int r = 0; r < 4; ++r) {
          float ar = __shfl(alpha, g * 4 + r);
          acc[0][r] *= ar; acc[1][r] *= ar; acc[2][r] *= ar; acc[3][r] *= ar;
        }
      }
      float p0[4], p1[4];
#pragma unroll
      for (int r = 0; r < 4; ++r) {
        p0[r] = fexp2(s0[r] - mrun);
        p1[r] = fexp2(s1[r] - mrun);
      }
      lrun += ((p0[0] + p0[1]) + (p0[2] + p0[3])) + ((p1[0] + p1[1]) + (p1[2] + p1[3]));
      u32x4 PL;
      PL[0] = cvtpk_bf16(p0[0], p0[1]); PL[1] = cvtpk_bf16(p0[2], p0[3]);
      PL[2] = cvtpk_bf16(p1[0], p1[1]); PL[3] = cvtpk_bf16(p1[2], p1[3]);
      short8 pa = __builtin_bit_cast(short8, PL);
      const u16* Vc = &Vs[u & 3][0];
      __builtin_amdgcn_s_setprio(1);
#pragma unroll
      for (int n = 0; n < 4; ++n) {
        short8 vf = *(const short8*)&Vc[n * 1024 + offv];
        acc[n] = MFMA(pa, vf, acc[n]);
      }
      __builtin_amdgcn_s_setprio(0);
    };

    stage(0, 0);
    if (nt > 1) stage(1, 64);

    for (int t = 0; t < nt; ++t) {
      const int kb = t * 64;
      const int rem = nt - 1 - t;

      if (rem >= 1) asm volatile("s_waitcnt vmcnt(2)" ::: "memory");
      else          asm volatile("s_waitcnt vmcnt(0)" ::: "memory");
      __builtin_amdgcn_sched_barrier(0);
      __builtin_amdgcn_s_barrier();
      __builtin_amdgcn_sched_barrier(0);

      if (rem >= 2) stage((t + 2) & 3, kb + 128);

      const u16* Kc = &Ks[t & 3][0];
      f32x4 sN0, sN1;
      __builtin_amdgcn_s_setprio(1);
      {
        const int ng = 2 * kh;
        short8 kf0 = *(const short8*)&Kc[ng * 1024 + off0];
        short8 kf1 = *(const short8*)&Kc[ng * 1024 + off1];
        f32x4 z = (f32x4)(0.f);
        z = MFMA(kf0, qf0, z); z = MFMA(kf1, qf1, z);
        sN0 = z;
        short8 kf2 = *(const short8*)&Kc[(ng + 1) * 1024 + off0];
        short8 kf3 = *(const short8*)&Kc[(ng + 1) * 1024 + off1];
        f32x4 w = (f32x4)(0.f);
        w = MFMA(kf2, qf0, w); w = MFMA(kf3, qf1, w);
        sN1 = w;
      }
      __builtin_amdgcn_s_setprio(0);

      if (t > 0) process(t - 1, sP0, sP1);
      sP0 = sN0; sP1 = sN1;
    }
    process(nt - 1, sP0, sP1);

    // ---- strip end: cross-g l combine, pairwise (m,l,O) merge, store ----
    float lt = lrun + __shfl_xor(lrun, 16);
    lt += __shfl_xor(lt, 32);

    __syncthreads();
    float* ab = (float*)&Ks[0][0] + qgrp * 1024;
    if (kh == 1) {
#pragma unroll
      for (int n = 0; n < 4; ++n)
#pragma unroll
        for (int r = 0; r < 4; ++r)
          ab[(4 * g + r) * 64 + 16 * n + r16] = acc[n][r];
      if (g == 0) {
        mlb[qgrp * 32 + r16 * 2]     = mrun;
        mlb[qgrp * 32 + r16 * 2 + 1] = lt;
      }
    }
    __syncthreads();
    if (kh == 0) {
#pragma unroll
      for (int r = 0; r < 4; ++r) {
        int q = 4 * g + r;
        float mA = __shfl(mrun, q);
        float lA = __shfl(lt, q);
        float mB = mlb[qgrp * 32 + q * 2];
        float lB = mlb[qgrp * 32 + q * 2 + 1];
        float ms = fmaxf(mA, mB);
        float cA = fexp2(mA - ms);
        float cB = fexp2(mB - ms);
        float linv = 1.0f / (lA * cA + lB * cB);
        int qr = q0 + qgrp * 16 + q;
        u16* orow = O + ((size_t)(b * Tc + qr)) * Hc + h * 64;
#pragma unroll
        for (int n = 0; n < 4; ++n) {
          float v = (acc[n][r] * cA + ab[q * 64 + 16 * n + r16] * cB) * linv;
          orow[n * 16 + r16] = f2bf(v);
        }
      }
    }
  }
}

// ---------------- launch ----------------
extern "C" void kernel_launch(void* const* d_in, const int* in_sizes, int n_in,
                              void* d_out, int out_size, void* d_ws, size_t ws_size,
                              hipStream_t stream) {
  const float* x = (const float*)d_in[0];
  const int* mask = (const int*)d_in[1];
  const float* Wqkv = (const float*)d_in[2];
  const float* bqkv = (const float*)d_in[3];
  const float* Wproj = (const float*)d_in[4];
  const float* bproj = (const float*)d_in[5];
  float* out = (float*)d_out;

  char* ws = (char*)d_ws;
  size_t off = 0;
  auto alloc = [&](size_t bytes) {
    char* p = ws + off;
    off += (bytes + 255) & ~(size_t)255;
    return p;
  };
  u16* xb     = (u16*)alloc((size_t)BTc * Hc * 2);
  u16* WqkvT  = (u16*)alloc((size_t)N3 * Hc * 2);
  u16* WprojT = (u16*)alloc((size_t)Hc * Hc * 2);
  u16* Qh     = (u16*)alloc((size_t)BTc * Hc * 2);
  u16* Kh     = (u16*)alloc((size_t)BTc * Hc * 2);
  u16* VT     = (u16*)alloc((size_t)BTc * Hc * 2);
  u32* ctr    = (u32*)alloc(256);
  u8*  flags  = (u8*)alloc(256);
  u16* Ob     = xb;  // alias: xb dead after GEMM1, reused for attention output

  k_prep<<<dim3(864 + BTc * Hc / 8 / 256), 256, 0, stream>>>(
      x, Wqkv, Wproj, xb, WqkvT, WprojT, mask, flags, ctr);
  k_gemm<<<dim3(N3 / 128, BTc / 128), 256, 0, stream>>>(xb, WqkvT, bqkv, Qh, Kh, VT,
                                                        BTc, N3, Hc);
  k_attn<<<dim3(512), 512, 0, stream>>>(Qh, Kh, VT, mask, flags, Ob, ctr);
  k_gemm2<<<dim3(12, 64), 256, 0, stream>>>(Ob, WprojT, bproj, out, Hc);
}